// Round 1
// 741.093 us; speedup vs baseline: 1.1153x; 1.1153x over previous
//
#include <hip/hip_runtime.h>

// NeighborCorrelator: out[b, 7i+j, h, w] =
//   inv_nx[b,h,w] * inv_ny[b,h+i-3,w+j-3] * sum_c x[b,c,h,w]*y[b,c,h+i-3,w+j-3]
//
// v2: conflict-free LDS + double-buffered single-barrier pipeline.
//  - X (A-fragments) loaded straight to registers (wave wv owns row h0+wv);
//    X norm via shfl_xor reduce. No X LDS traffic at all.
//  - Y staged as [hy][cg=c/8][w2(22)][c8] bf16 (16B slots): ds_write_b128 /
//    ds_read_b128 at 16B lane stride -> bank-bandwidth-minimal.
//    No zero pad columns: B-frag lanes with n>21 clamp to w2=21; their products
//    land only in acc diagonals j>=7 which the epilogue discards.
//  - Double-buffered chunk loop, ONE barrier per chunk: loads for chunk k+1
//    issue before compute of chunk k, ds_write after -> HBM latency hidden.
//  - Epilogue restaged through LDS (stride-260 pad) -> coalesced 64B out rows.
//  - XCD-contiguous block remap (1024 wgs % 8 == 0 -> bijective).

#define H_ 256
#define W_ 256
#define C_ 256
#define B_ 4
#define TH 16
#define TW 16
#define KCH 32
#define NCHUNK (C_ / KCH)  // 8
#define HAL (TH + 6)       // 22
#define WAL (TW + 6)       // 22
#define PLANE (H_ * W_)    // 65536

typedef __attribute__((ext_vector_type(8))) short short8;
typedef __attribute__((ext_vector_type(4))) float floatx4;
typedef __attribute__((ext_vector_type(4))) unsigned uint32x4;

// pack two floats to bf16x2 (RNE), a -> low half (even channel)
__device__ __forceinline__ unsigned bfpair(float a, float b) {
  unsigned ua = __float_as_uint(a), ub = __float_as_uint(b);
  ua = (ua + 0x7FFFu + ((ua >> 16) & 1u)) >> 16;
  ub = (ub + 0x7FFFu + ((ub >> 16) & 1u)) & 0xFFFF0000u;
  return ub | ua;
}

__global__ __launch_bounds__(1024) void ncorr(const float* __restrict__ x,
                                              const float* __restrict__ y,
                                              float* __restrict__ out) {
  // Yb slot layout: slot16 = (hy*4 + cg)*22 + wy ; holds channels cg*8..cg*8+7
  // 2 buffers x 22*4*22*16B = 2 x 30976 B = 61952 B
  __shared__ __align__(16) short Yb[2][HAL * 4 * WAL * 8];
  __shared__ float sxl[TH * TW];   // 1024 B
  __shared__ float syl[HAL * WAL]; // 1936 B   (total 64912 B)
  float* Ob = (float*)&Yb[0][0];   // epilogue alias: 49*260*4 = 50960 B

  const int t = threadIdx.x;

  // ---- XCD-contiguous remap (bijective: 1024 % 8 == 0) ----
  int id = (blockIdx.z * gridDim.y + blockIdx.y) * gridDim.x + blockIdx.x;
  int sw = (id & 7) * 128 + (id >> 3);
  const int b = sw >> 8;
  const int h0 = ((sw >> 4) & 15) * TH;
  const int w0 = (sw & 15) * TW;

  if (t < HAL * WAL) syl[t] = 0.f;

  const int lane = t & 63;
  const int wv = t >> 6;  // wave id == local output h row
  const int q = lane >> 4;
  const int lr = lane & 15;

  // X direct-to-reg: lane (q,lr) of wave wv loads channels q*8+j at (h0+wv, w0+lr)
  const int xbase = ((b * C_ + q * 8) * H_ + (h0 + wv)) * W_ + (w0 + lr);

  // Y staging: thread t<968 owns slot s=t: 16 channels (cg2*16..+15) at (hy,wy)
  const bool yact = (t < 968);
  bool yin = false;
  int ybase = 0, yslot = 0, ypos = 0;
  if (yact) {
    int cg2 = t / 484;
    int r = t - cg2 * 484;
    int hy = r / 22;
    int wy = r - hy * 22;
    int gy = h0 - 3 + hy, gx = w0 - 3 + wy;
    yin = (gy >= 0) && (gy < H_) && (gx >= 0) && (gx < W_);
    ybase = ((b * C_ + cg2 * 16) * H_ + (yin ? gy : 0)) * W_ + (yin ? gx : 0);
    yslot = (hy * 4 + cg2 * 2) * 22 + wy;  // first 8ch; second 8ch at +22 slots
    ypos = hy * 22 + wy;
  }
  float sxacc = 0.f, syacc = 0.f;

  floatx4 acc[7][2];
#pragma unroll
  for (int i = 0; i < 7; i++) {
    acc[i][0] = (floatx4){0.f, 0.f, 0.f, 0.f};
    acc[i][1] = (floatx4){0.f, 0.f, 0.f, 0.f};
  }

  // per-lane B column offsets (n>21 clamps to 21; j>=7 diagonals are discarded)
  const int w2a = lr;
  const int w2b = (lr < 6) ? (16 + lr) : 21;

  float xr[2][8];
  float yr[2][16];
#pragma unroll
  for (int s = 0; s < 2; s++) {
#pragma unroll
    for (int k = 0; k < 16; k++) yr[s][k] = 0.f;
  }

  // ---- prologue: chunk 0 ----
#pragma unroll
  for (int j = 0; j < 8; j++) xr[0][j] = x[xbase + j * PLANE];
  if (yact) {
    if (yin) {
#pragma unroll
      for (int k = 0; k < 16; k++) yr[0][k] = y[ybase + k * PLANE];
    }
    unsigned p[8];
#pragma unroll
    for (int k = 0; k < 8; k++) {
      syacc += yr[0][2 * k] * yr[0][2 * k] + yr[0][2 * k + 1] * yr[0][2 * k + 1];
      p[k] = bfpair(yr[0][2 * k], yr[0][2 * k + 1]);
    }
    uint32x4 v0 = {p[0], p[1], p[2], p[3]};
    uint32x4 v1 = {p[4], p[5], p[6], p[7]};
    *(uint32x4*)&Yb[0][yslot * 8] = v0;
    *(uint32x4*)&Yb[0][(yslot + 22) * 8] = v1;
  }
  __syncthreads();

  // ---- main loop: chunk ch lives in buf/reg slot ch&1; ONE barrier/chunk ----
#pragma unroll
  for (int ch = 0; ch < NCHUNK; ch++) {
    const int cur = ch & 1, nxt = cur ^ 1;
    const int cof = (ch + 1) * KCH * PLANE;
    if (ch < NCHUNK - 1) {
#pragma unroll
      for (int j = 0; j < 8; j++) xr[nxt][j] = x[xbase + cof + j * PLANE];
      if (yact && yin) {
#pragma unroll
        for (int k = 0; k < 16; k++) yr[nxt][k] = y[ybase + cof + k * PLANE];
      }
    }
    // pack A for chunk ch (loads completed before previous barrier)
    uint32x4 av;
#pragma unroll
    for (int k = 0; k < 4; k++) {
      sxacc += xr[cur][2 * k] * xr[cur][2 * k] + xr[cur][2 * k + 1] * xr[cur][2 * k + 1];
      av[k] = bfpair(xr[cur][2 * k], xr[cur][2 * k + 1]);
    }
    short8 A = __builtin_bit_cast(short8, av);
    // compute: B[k=q*8+j][n] from Yb slot ((wv+i)*4+q)*22 + w2
#pragma unroll
    for (int i = 0; i < 7; i++) {
      const int rb = ((wv + i) * 4 + q) * 22;
      short8 B0 = *(const short8*)&Yb[cur][(rb + w2a) * 8];
      acc[i][0] = __builtin_amdgcn_mfma_f32_16x16x32_bf16(A, B0, acc[i][0], 0, 0, 0);
      short8 B1 = *(const short8*)&Yb[cur][(rb + w2b) * 8];
      acc[i][1] = __builtin_amdgcn_mfma_f32_16x16x32_bf16(A, B1, acc[i][1], 0, 0, 0);
    }
    // stage chunk ch+1 into the other buffer (waits its loads via vmcnt)
    if (ch < NCHUNK - 1 && yact) {
      unsigned p[8];
#pragma unroll
      for (int k = 0; k < 8; k++) {
        syacc += yr[nxt][2 * k] * yr[nxt][2 * k] + yr[nxt][2 * k + 1] * yr[nxt][2 * k + 1];
        p[k] = bfpair(yr[nxt][2 * k], yr[nxt][2 * k + 1]);
      }
      uint32x4 v0 = {p[0], p[1], p[2], p[3]};
      uint32x4 v1 = {p[4], p[5], p[6], p[7]};
      *(uint32x4*)&Yb[nxt][yslot * 8] = v0;
      *(uint32x4*)&Yb[nxt][(yslot + 22) * 8] = v1;
    }
    __syncthreads();
  }

  // ---- norms ----
  float xs = sxacc;
  xs += __shfl_xor(xs, 16);
  xs += __shfl_xor(xs, 32);
  if (q == 0) sxl[wv * 16 + lr] = 1.f / fmaxf(sqrtf(xs), 1e-12f);
  if (yact) atomicAdd(&syl[ypos], syacc);
  __syncthreads();
  if (t < HAL * WAL) syl[t] = 1.f / fmaxf(sqrtf(syl[t]), 1e-12f);
  __syncthreads();

  // ---- epilogue: restage through LDS for coalesced 64B row writes ----
  // C/D layout: col(n) = lane&15 (+16*nt), row(m) = q*4 + r
#pragma unroll
  for (int i = 0; i < 7; i++) {
#pragma unroll
    for (int nt = 0; nt < 2; nt++) {
      const int n = nt * 16 + lr;
#pragma unroll
      for (int r = 0; r < 4; r++) {
        const int m = q * 4 + r;
        const int j = n - m;
        if (j >= 0 && j < 7) {
          float v = acc[i][nt][r] * sxl[wv * 16 + m] * syl[(wv + i) * 22 + n];
          Ob[(7 * i + j) * 260 + wv * 16 + m] = v;  // stride 260: no 4B-store bank pileup
        }
      }
    }
  }
  __syncthreads();
  for (int idx = t; idx < 49 * 256; idx += 1024) {
    const int chn = idx >> 8;
    const int rem = idx & 255;
    __builtin_nontemporal_store(
        Ob[chn * 260 + rem],
        &out[((b * 49 + chn) * H_ + h0 + (rem >> 4)) * W_ + (w0 + (rem & 15))]);
  }
}

extern "C" void kernel_launch(void* const* d_in, const int* in_sizes, int n_in,
                              void* d_out, int out_size, void* d_ws, size_t ws_size,
                              hipStream_t stream) {
  const float* x = (const float*)d_in[0];
  const float* y = (const float*)d_in[1];
  float* out = (float*)d_out;
  dim3 grid(W_ / TW, H_ / TH, B_);
  ncorr<<<grid, 1024, 0, stream>>>(x, y, out);
}